// Round 7
// baseline (229.651 us; speedup 1.0000x reference)
//
#include <hip/hip_runtime.h>

#define SHIFT 4

typedef __bf16 bf16x8 __attribute__((ext_vector_type(8)));
typedef __bf16 bf16x4 __attribute__((ext_vector_type(4)));
typedef float  f32x4  __attribute__((ext_vector_type(4)));

// LDS leading dims (elements). All rows 16B-aligned; strides chosen to spread
// 16-lane b128 column reads across banks.
#define LDA 104  // h / u row tiles: [64][LDA]
#define LDQ 40   // q/k: [3][64][LDQ]
#define LDV 72   // v transposed: [3][32][LDV]
#define LDP 72   // P scratch: [64][LDP]
#define LDW 104  // staged weight chunk: [96][LDW]

// ws layout (bf16 elements unless noted):
//   frag region  @ 0      : 72 frags x 512  (qkv c*18+t*3+ks: 0..53; proj 54+t*3+ks)
//                           lane L holds 8 contraction vals for B-frag
//   w1T          @ 36864  : [384 outcols][96 k]
//   w2 chunked   @ 73728  : [4 chunks][96 outcols][96 k-in-chunk]
//   bias f32     @ byte 221184 : [3][64][64] full rel-pos bias
#define WS_FRAG 0
#define WS_W1T  36864
#define WS_W2C  73728
#define WS_BIAS_BYTES 221184

// ---------------------------------------------------------------------------
// Kernel 0: weight prep + full rel-pos bias tensor.
// ---------------------------------------------------------------------------
__global__ __launch_bounds__(256)
void swin_prep_kernel(const float* __restrict__ qkvw, const float* __restrict__ projw,
                      const float* __restrict__ w1, const float* __restrict__ w2,
                      const float* __restrict__ btab,
                      __bf16* __restrict__ ws)
{
  const int i = blockIdx.x * 256 + threadIdx.x;
  if (i < 36864) {                       // fragment-ordered qkv + proj
    const int fi = i >> 9, e = i & 511;
    const int lane = e >> 3, j = e & 7;
    const int l15 = lane & 15;
    const int kk  = (lane >> 4) * 8 + j;
    float v;
    if (fi < 54) {                       // qkvw [96][288]
      const int c = fi / 18, rem = fi % 18, t = rem / 3, ks = rem % 3;
      v = qkvw[(ks * 32 + kk) * 288 + c * 96 + t * 16 + l15];
    } else {                             // projw [96][96]
      const int f2 = fi - 54, t = f2 / 3, ks = f2 % 3;
      v = projw[(ks * 32 + kk) * 96 + t * 16 + l15];
    }
    ws[i] = (__bf16)v;
  } else if (i < 73728) {                // w1T [384][96]; w1 is [96][384]
    const int j = i - WS_W1T;
    const int col = j / 96, kk = j - col * 96;
    ws[i] = (__bf16)w1[kk * 384 + col];
  } else if (i < 110592) {               // w2 chunked; w2 is [384][96]
    const int j = i - WS_W2C;
    const int c = j / 9216, r2 = j - c * 9216;
    const int col = r2 / 96, kk = r2 - col * 96;
    ws[i] = (__bf16)w2[(c * 96 + kk) * 96 + col];
  } else {                               // bias_full[h][n][m]
    const int jj = i - 110592;           // < 12288
    const int h = jj >> 12, n = (jj >> 6) & 63, m = jj & 63;
    const int dy = (n >> 3) - (m >> 3), dx = (n & 7) - (m & 7);
    float* biasf = (float*)((char*)ws + WS_BIAS_BYTES);
    biasf[jj] = btab[((dy + 7) * 15 + (dx + 7)) * 3 + h];
  }
}

// ---------------------------------------------------------------------------
// Fused kernel: LN1 + shift/partition + MHSA + proj + residual + LN2 + MLP +
// residual, one block per 8x8 window. 256 threads = 4 waves; wave wv owns
// rows 16wv..16wv+15 end-to-end. MLP weights staged into LDS regions that
// are dead after attention (q/k/v/p).
// ---------------------------------------------------------------------------
__global__ __launch_bounds__(256, 2)
void swin_block_kernel(const float* __restrict__ x,
                       const float* __restrict__ ln1g, const float* __restrict__ ln1b,
                       const __bf16* __restrict__ ws, const float* __restrict__ qkvb,
                       const float* __restrict__ ln2g, const float* __restrict__ ln2b,
                       float* __restrict__ out)
{
  __shared__ __align__(16) char lds[67072];
  __bf16* h_s = (__bf16*)lds;              // [64][LDA]     13312 B (h, attn-out, h2)
  __bf16* q_s = (__bf16*)(lds + 13312);    // [3][64][LDQ]  15360 B
  __bf16* k_s = (__bf16*)(lds + 28672);    // [3][64][LDQ]  15360 B
  __bf16* v_s = (__bf16*)(lds + 44032);    // [3][32][LDV]  13824 B
  __bf16* p_s = (__bf16*)(lds + 57856);    // [64][LDP]      9216 B
  // MLP-phase aliases (q/k/v/p dead after attention):
  __bf16* w1_s = (__bf16*)(lds + 13312);   // [96][LDW]     19968 B
  __bf16* w2_s = (__bf16*)(lds + 33280);   // [96][LDW]     19968 B
  __bf16* u_s  = (__bf16*)(lds + 53248);   // [64][LDA]     13312 B

  const float* biasf = (const float*)((const char*)ws + WS_BIAS_BYTES);

  const int tid  = threadIdx.x;
  const int lane = tid & 63;
  const int wv   = tid >> 6;
  const int l15  = lane & 15;
  const int g4   = lane >> 4;
  const int blk  = blockIdx.x;          // b*256 + wy*16 + wx
  const int b    = blk >> 8;
  const int wy   = (blk >> 4) & 15;
  const int wx   = blk & 15;

  // ---------------- Phase 1: LayerNorm1 (4 lanes per token; wave-local) -----
  {
    const int t = tid >> 2, p = tid & 3;
    const int ti = t >> 3, tj = t & 7;
    const int iy = (wy * 8 + ti + SHIFT) & 127;
    const int ix = (wx * 8 + tj + SHIFT) & 127;
    const float* rowp = x + ((size_t)(b * 16384 + iy * 128 + ix)) * 96 + p * 24;
    float vb[24];
    float s = 0.f, ss = 0.f;
#pragma unroll
    for (int u = 0; u < 6; ++u) {
      f32x4 f = *(const f32x4*)(rowp + 4 * u);
#pragma unroll
      for (int e = 0; e < 4; ++e) { float q = f[e]; vb[4*u+e] = q; s += q; ss += q*q; }
    }
    s  += __shfl_xor(s, 1);  s  += __shfl_xor(s, 2);
    ss += __shfl_xor(ss, 1); ss += __shfl_xor(ss, 2);
    const float mean = s * (1.f / 96.f);
    const float var  = ss * (1.f / 96.f) - mean * mean;
    const float rstd = rsqrtf(var + 1e-5f);
#pragma unroll
    for (int u = 0; u < 6; ++u) {
      f32x4 gg = *(const f32x4*)(ln1g + p * 24 + 4 * u);
      f32x4 bb = *(const f32x4*)(ln1b + p * 24 + 4 * u);
      f32x4 nv;
#pragma unroll
      for (int e = 0; e < 4; ++e) nv[e] = (vb[4*u+e] - mean) * rstd * gg[e] + bb[e];
      *(bf16x4*)&h_s[t * LDA + p * 24 + 4 * u] = __builtin_convertvector(nv, bf16x4);
    }
  }
  // no barrier: each wave reads only its own h rows below

  // ---------------- Phase 2: QKV projection, B-frags direct from global -----
  const float qscale = 0.17677669529663687f;  // 1/sqrt(32)
  const __bf16* fbase = ws + (size_t)lane * 8;
  const int rowb = 16 * wv;
  for (int c = 0; c < 3; ++c) {
    bf16x8 wf[6][3];
#pragma unroll
    for (int t = 0; t < 6; ++t)
#pragma unroll
      for (int ks = 0; ks < 3; ++ks)
        wf[t][ks] = *(const bf16x8*)(fbase + (size_t)(c * 18 + t * 3 + ks) * 512);
    f32x4 acc[6];
#pragma unroll
    for (int t = 0; t < 6; ++t) {
      const float bv = qkvb[c * 96 + t * 16 + l15];
      f32x4 a4 = {bv, bv, bv, bv};
      acc[t] = a4;
    }
#pragma unroll
    for (int ks = 0; ks < 3; ++ks) {
      bf16x8 a = *(const bf16x8*)&h_s[(rowb + l15) * LDA + ks * 32 + 8 * g4];
#pragma unroll
      for (int t = 0; t < 6; ++t)
        acc[t] = __builtin_amdgcn_mfma_f32_16x16x32_bf16(a, wf[t][ks], acc[t], 0, 0, 0);
    }
    if (c < 2) {
#pragma unroll
      for (int t = 0; t < 6; ++t) {
        const int head = t >> 1, dim = (t & 1) * 16 + l15;
#pragma unroll
        for (int r = 0; r < 4; ++r) {
          const int tok = rowb + 4 * g4 + r;
          if (c == 0) q_s[(head * 64 + tok) * LDQ + dim] = (__bf16)(acc[t][r] * qscale);
          else        k_s[(head * 64 + tok) * LDQ + dim] = (__bf16)acc[t][r];
        }
      }
    } else {  // v transposed [head][dim][tok]; 4 regs = 4 consecutive toks
#pragma unroll
      for (int t = 0; t < 6; ++t) {
        const int head = t >> 1, dim = (t & 1) * 16 + l15;
        *(bf16x4*)&v_s[(head * 32 + dim) * LDV + rowb + 4 * g4] =
            __builtin_convertvector(acc[t], bf16x4);
      }
    }
  }

  __syncthreads();   // k_s/v_s visible to all waves

  // ---------------- Phase 3: attention, head by head ----------------
  int qry[4], qrx[4];
#pragma unroll
  for (int r = 0; r < 4; ++r) {
    const int row = rowb + 4 * g4 + r;
    const int ti2 = row >> 3, tj2 = row & 7;
    qry[r] = (wy == 15) ? (ti2 < 4 ? 1 : 2) : 0;
    qrx[r] = (wx == 15) ? (tj2 < 4 ? 1 : 2) : 0;
  }
  const f32x4 zf = {0.f, 0.f, 0.f, 0.f};
  for (int h = 0; h < 3; ++h) {
    const float* bh = biasf + h * 4096;
    float bv[4][4];
#pragma unroll
    for (int n = 0; n < 4; ++n)
#pragma unroll
      for (int r = 0; r < 4; ++r)
        bv[n][r] = bh[(rowb + 4 * g4 + r) * 64 + n * 16 + l15];

    bf16x8 aq = *(const bf16x8*)&q_s[(h * 64 + rowb + l15) * LDQ + 8 * g4];
    f32x4 sc[4];
#pragma unroll
    for (int n = 0; n < 4; ++n) {
      bf16x8 bk = *(const bf16x8*)&k_s[(h * 64 + n * 16 + l15) * LDQ + 8 * g4];
      sc[n] = __builtin_amdgcn_mfma_f32_16x16x32_bf16(aq, bk, zf, 0, 0, 0);
    }
#pragma unroll
    for (int n = 0; n < 4; ++n) {
      const int colt = n * 16 + l15;
      const int ki = colt >> 3, kj = colt & 7;
      const int kry = (wy == 15) ? (ki < 4 ? 1 : 2) : 0;
      const int krx = (wx == 15) ? (kj < 4 ? 1 : 2) : 0;
#pragma unroll
      for (int r = 0; r < 4; ++r) {
        const float mk = (qry[r] == kry && qrx[r] == krx) ? 0.f : -100.f;
        sc[n][r] += bv[n][r] + mk;
      }
    }
    float mx[4], sm[4];
#pragma unroll
    for (int r = 0; r < 4; ++r) {
      float m = fmaxf(fmaxf(sc[0][r], sc[1][r]), fmaxf(sc[2][r], sc[3][r]));
      m = fmaxf(m, __shfl_xor(m, 1)); m = fmaxf(m, __shfl_xor(m, 2));
      m = fmaxf(m, __shfl_xor(m, 4)); m = fmaxf(m, __shfl_xor(m, 8));
      mx[r] = m; sm[r] = 0.f;
    }
#pragma unroll
    for (int n = 0; n < 4; ++n)
#pragma unroll
      for (int r = 0; r < 4; ++r) {
        float p = __expf(sc[n][r] - mx[r]); sc[n][r] = p; sm[r] += p;
      }
#pragma unroll
    for (int r = 0; r < 4; ++r) {
      float s2 = sm[r];
      s2 += __shfl_xor(s2, 1); s2 += __shfl_xor(s2, 2);
      s2 += __shfl_xor(s2, 4); s2 += __shfl_xor(s2, 8);
      sm[r] = __builtin_amdgcn_rcpf(s2);
    }
#pragma unroll
    for (int n = 0; n < 4; ++n)
#pragma unroll
      for (int r = 0; r < 4; ++r)
        p_s[(rowb + 4 * g4 + r) * LDP + n * 16 + l15] = (__bf16)sc[n][r];
    f32x4 ov[2] = {zf, zf};
#pragma unroll
    for (int ks = 0; ks < 2; ++ks) {
      bf16x8 pa = *(const bf16x8*)&p_s[(rowb + l15) * LDP + ks * 32 + 8 * g4];
#pragma unroll
      for (int t2 = 0; t2 < 2; ++t2) {
        bf16x8 vb2 = *(const bf16x8*)&v_s[(h * 32 + t2 * 16 + l15) * LDV + ks * 32 + 8 * g4];
        ov[t2] = __builtin_amdgcn_mfma_f32_16x16x32_bf16(pa, vb2, ov[t2], 0, 0, 0);
      }
    }
#pragma unroll
    for (int t2 = 0; t2 < 2; ++t2)
#pragma unroll
      for (int r = 0; r < 4; ++r)
        h_s[(rowb + 4 * g4 + r) * LDA + h * 32 + t2 * 16 + l15] = (__bf16)(ov[t2][r] * sm[r]);
  }
  // no barrier: proj reads only this wave's h rows

  // ---------------- Phase 4: output projection (B-frags direct) -------------
  f32x4 po[6];
#pragma unroll
  for (int t = 0; t < 6; ++t) po[t] = zf;
#pragma unroll
  for (int ks = 0; ks < 3; ++ks) {
    bf16x8 a = *(const bf16x8*)&h_s[(rowb + l15) * LDA + ks * 32 + 8 * g4];
#pragma unroll
    for (int t = 0; t < 6; ++t) {
      bf16x8 bb = *(const bf16x8*)(fbase + (size_t)(54 + t * 3 + ks) * 512);
      po[t] = __builtin_amdgcn_mfma_f32_16x16x32_bf16(a, bb, po[t], 0, 0, 0);
    }
  }

  // ---------------- Phase 4.5: residual + LN2 fully in registers ------------
  size_t gbase[4];
  float xm[6][4];
#pragma unroll
  for (int r = 0; r < 4; ++r) {
    const int row = rowb + 4 * g4 + r;
    const int ti2 = row >> 3, tj2 = row & 7;
    const int iy = (wy * 8 + ti2 + SHIFT) & 127;
    const int ix = (wx * 8 + tj2 + SHIFT) & 127;
    gbase[r] = ((size_t)(b * 16384 + iy * 128 + ix)) * 96;
#pragma unroll
    for (int t = 0; t < 6; ++t)
      xm[t][r] = x[gbase[r] + t * 16 + l15] + po[t][r];
  }
  {
    float g6[6], b6[6];
#pragma unroll
    for (int t = 0; t < 6; ++t) { g6[t] = ln2g[t * 16 + l15]; b6[t] = ln2b[t * 16 + l15]; }
#pragma unroll
    for (int r = 0; r < 4; ++r) {
      float s = 0.f, ss = 0.f;
#pragma unroll
      for (int t = 0; t < 6; ++t) { s += xm[t][r]; ss += xm[t][r] * xm[t][r]; }
      s  += __shfl_xor(s, 1);  s  += __shfl_xor(s, 2);
      s  += __shfl_xor(s, 4);  s  += __shfl_xor(s, 8);
      ss += __shfl_xor(ss, 1); ss += __shfl_xor(ss, 2);
      ss += __shfl_xor(ss, 4); ss += __shfl_xor(ss, 8);
      const float mean = s * (1.f / 96.f);
      const float var  = ss * (1.f / 96.f) - mean * mean;
      const float rstd = rsqrtf(var + 1e-5f);
#pragma unroll
      for (int t = 0; t < 6; ++t) {
        const float h2 = (xm[t][r] - mean) * rstd * g6[t] + b6[t];
        h_s[(rowb + 4 * g4 + r) * LDA + t * 16 + l15] = (__bf16)h2;
      }
    }
  }

  __syncthreads();   // all q/k/v/p reads done -> regions reusable for weights

  // ---------------- Phase 5: MLP (LDS-staged weight chunks) -----------------
  f32x4 acc[6];
#pragma unroll
  for (int t = 0; t < 6; ++t) acc[t] = zf;

  for (int c = 0; c < 4; ++c) {
    // stage w1 chunk [96][96] and w2 chunk [96][96] (16B vector copies)
    for (int m = tid; m < 2304; m += 256) {
      const int mat = (m >= 1152) ? 1 : 0;
      const int mm = m - mat * 1152;
      const int row = mm / 12, q4 = mm - row * 12;
      const __bf16* src = ws + WS_W1T + c * 9216 + mat * (WS_W2C - WS_W1T)
                        + row * 96 + q4 * 8;
      __bf16* dst = (__bf16*)(lds + 13312 + mat * 19968) + row * LDW + q4 * 8;
      *(uint4*)dst = *(const uint4*)src;
    }
    __syncthreads();
    f32x4 ua[6];
#pragma unroll
    for (int t = 0; t < 6; ++t) ua[t] = zf;
#pragma unroll
    for (int ks = 0; ks < 3; ++ks) {
      bf16x8 a = *(const bf16x8*)&h_s[(rowb + l15) * LDA + ks * 32 + 8 * g4];
#pragma unroll
      for (int t = 0; t < 6; ++t) {
        bf16x8 bb = *(const bf16x8*)&w1_s[(t * 16 + l15) * LDW + ks * 32 + 8 * g4];
        ua[t] = __builtin_amdgcn_mfma_f32_16x16x32_bf16(a, bb, ua[t], 0, 0, 0);
      }
    }
    // gelu -> u_s (wave-local rows)
#pragma unroll
    for (int t = 0; t < 6; ++t)
#pragma unroll
      for (int r = 0; r < 4; ++r) {
        const float v = ua[t][r];
        const float a3 = 0.7978845608028654f * (v + 0.044715f * v * v * v);
        const float e = __expf(2.f * a3);
        const float g = v - v * __builtin_amdgcn_rcpf(e + 1.f);
        u_s[(rowb + 4 * g4 + r) * LDA + t * 16 + l15] = (__bf16)g;
      }
#pragma unroll
    for (int ks = 0; ks < 3; ++ks) {
      bf16x8 pa = *(const bf16x8*)&u_s[(rowb + l15) * LDA + ks * 32 + 8 * g4];
#pragma unroll
      for (int t = 0; t < 6; ++t) {
        bf16x8 bb = *(const bf16x8*)&w2_s[(t * 16 + l15) * LDW + ks * 32 + 8 * g4];
        acc[t] = __builtin_amdgcn_mfma_f32_16x16x32_bf16(pa, bb, acc[t], 0, 0, 0);
      }
    }
    __syncthreads();   // weight buffers reusable next chunk
  }

  // ---------------- Epilogue: out = x_mid + mlp ----------------
#pragma unroll
  for (int r = 0; r < 4; ++r)
#pragma unroll
    for (int t = 0; t < 6; ++t)
      out[gbase[r] + t * 16 + l15] = xm[t][r] + acc[t][r];
}

extern "C" void kernel_launch(void* const* d_in, const int* in_sizes, int n_in,
                              void* d_out, int out_size, void* d_ws, size_t ws_size,
                              hipStream_t stream) {
  (void)in_sizes; (void)n_in; (void)out_size; (void)ws_size;
  const float* x     = (const float*)d_in[0];
  const float* ln1g  = (const float*)d_in[1];
  const float* ln1b  = (const float*)d_in[2];
  const float* qkvw  = (const float*)d_in[3];
  const float* qkvb  = (const float*)d_in[4];
  const float* projw = (const float*)d_in[5];
  const float* btab  = (const float*)d_in[6];
  const float* ln2g  = (const float*)d_in[7];
  const float* ln2b  = (const float*)d_in[8];
  const float* w1    = (const float*)d_in[9];
  const float* w2    = (const float*)d_in[10];
  float* out = (float*)d_out;
  __bf16* ws = (__bf16*)d_ws;

  // 122880 items = 110592 weight elems + 12288 bias elems
  swin_prep_kernel<<<480, 256, 0, stream>>>(qkvw, projw, w1, w2, btab, ws);
  swin_block_kernel<<<4096, 256, 0, stream>>>(x, ln1g, ln1b, ws, qkvb, ln2g, ln2b, out);
}

// Round 8
// 196.858 us; speedup vs baseline: 1.1666x; 1.1666x over previous
//
#include <hip/hip_runtime.h>

#define SHIFT 4

typedef __bf16 bf16x8 __attribute__((ext_vector_type(8)));
typedef __bf16 bf16x4 __attribute__((ext_vector_type(4)));
typedef float  f32x4  __attribute__((ext_vector_type(4)));

// LDS leading dims (elements).
#define LDA 104  // h/u row tiles: [rows][LDA]
#define LDQ 40   // k (and q-scratch): [3][64][LDQ]
#define LDV 72   // v transposed: [3][32][LDV]
#define LDW 104  // staged weight chunk: [96][LDW]

// ws layout (bf16 elements unless noted):
//   frag region @ 0     : 72 frags x 512 (qkv c*18+t*3+ks: 0..53; proj 54+t*3+ks)
//                         lane L holds 8 contraction vals for the MFMA B-frag
//   w1T         @ 36864 : [4 chunks][96 outcols][96 k]
//   w2 chunked  @ 73728 : [4 chunks][96 outcols][96 k-in-chunk]
//   bias f32    @ byte 221184 : [3][64][64] full rel-pos bias
#define WS_W1T  36864
#define WS_W2C  73728
#define WS_BIAS_BYTES 221184

// ---------------------------------------------------------------------------
// Kernel 0: weight prep + full rel-pos bias tensor (identical to R7).
// ---------------------------------------------------------------------------
__global__ __launch_bounds__(256)
void swin_prep_kernel(const float* __restrict__ qkvw, const float* __restrict__ projw,
                      const float* __restrict__ w1, const float* __restrict__ w2,
                      const float* __restrict__ btab,
                      __bf16* __restrict__ ws)
{
  const int i = blockIdx.x * 256 + threadIdx.x;
  if (i < 36864) {                       // fragment-ordered qkv + proj
    const int fi = i >> 9, e = i & 511;
    const int lane = e >> 3, j = e & 7;
    const int l15 = lane & 15;
    const int kk  = (lane >> 4) * 8 + j;
    float v;
    if (fi < 54) {                       // qkvw [96][288]
      const int c = fi / 18, rem = fi % 18, t = rem / 3, ks = rem % 3;
      v = qkvw[(ks * 32 + kk) * 288 + c * 96 + t * 16 + l15];
    } else {                             // projw [96][96]
      const int f2 = fi - 54, t = f2 / 3, ks = f2 % 3;
      v = projw[(ks * 32 + kk) * 96 + t * 16 + l15];
    }
    ws[i] = (__bf16)v;
  } else if (i < 73728) {                // w1T [384][96]; w1 is [96][384]
    const int j = i - WS_W1T;
    const int col = j / 96, kk = j - col * 96;
    ws[i] = (__bf16)w1[kk * 384 + col];
  } else if (i < 110592) {               // w2 chunked; w2 is [384][96]
    const int j = i - WS_W2C;
    const int c = j / 9216, r2 = j - c * 9216;
    const int col = r2 / 96, kk = r2 - col * 96;
    ws[i] = (__bf16)w2[(c * 96 + kk) * 96 + col];
  } else {                               // bias_full[h][n][m]
    const int jj = i - 110592;           // < 12288
    const int h = jj >> 12, n = (jj >> 6) & 63, m = jj & 63;
    const int dy = (n >> 3) - (m >> 3), dx = (n & 7) - (m & 7);
    float* biasf = (float*)((char*)ws + WS_BIAS_BYTES);
    biasf[jj] = btab[((dy + 7) * 15 + (dx + 7)) * 3 + h];
  }
}

// ---------------------------------------------------------------------------
// Kernel 1: LN1 + shift/partition + MHSA + proj + residual.
// LDS diet: 42.5 KB -> 3 blocks/CU. q lives in registers (k_s used as
// scratch before k overwrites it); P aliases dead h region; attn-out in regs.
// One barrier total.
// ---------------------------------------------------------------------------
__global__ __launch_bounds__(256, 3)
void swin_attn_kernel(const float* __restrict__ x,
                      const float* __restrict__ ln1g, const float* __restrict__ ln1b,
                      const __bf16* __restrict__ ws, const float* __restrict__ qkvb,
                      float* __restrict__ out)
{
  __shared__ __align__(16) char lds[42496];
  __bf16* h_s = (__bf16*)lds;              // [64][LDA]    13312 B (h, P, attn-out)
  __bf16* k_s = (__bf16*)(lds + 13312);    // [3][64][LDQ] 15360 B (q-scratch, then k)
  __bf16* v_s = (__bf16*)(lds + 28672);    // [3][32][LDV] 13824 B

  const float* biasf = (const float*)((const char*)ws + WS_BIAS_BYTES);

  const int tid  = threadIdx.x;
  const int lane = tid & 63;
  const int wv   = tid >> 6;
  const int l15  = lane & 15;
  const int g4   = lane >> 4;
  const int blk  = blockIdx.x;          // b*256 + wy*16 + wx
  const int b    = blk >> 8;
  const int wy   = (blk >> 4) & 15;
  const int wx   = blk & 15;

  // ---------------- Phase 1: LayerNorm1 (4 lanes/token; wave-local rows) ----
  {
    const int t = tid >> 2, p = tid & 3;
    const int ti = t >> 3, tj = t & 7;
    const int iy = (wy * 8 + ti + SHIFT) & 127;
    const int ix = (wx * 8 + tj + SHIFT) & 127;
    const float* rowp = x + ((size_t)(b * 16384 + iy * 128 + ix)) * 96 + p * 24;
    float vb[24];
    float s = 0.f, ss = 0.f;
#pragma unroll
    for (int u = 0; u < 6; ++u) {
      f32x4 f = *(const f32x4*)(rowp + 4 * u);
#pragma unroll
      for (int e = 0; e < 4; ++e) { float q = f[e]; vb[4*u+e] = q; s += q; ss += q*q; }
    }
    s  += __shfl_xor(s, 1);  s  += __shfl_xor(s, 2);
    ss += __shfl_xor(ss, 1); ss += __shfl_xor(ss, 2);
    const float mean = s * (1.f / 96.f);
    const float var  = ss * (1.f / 96.f) - mean * mean;
    const float rstd = rsqrtf(var + 1e-5f);
#pragma unroll
    for (int u = 0; u < 6; ++u) {
      f32x4 gg = *(const f32x4*)(ln1g + p * 24 + 4 * u);
      f32x4 bb = *(const f32x4*)(ln1b + p * 24 + 4 * u);
      f32x4 nv;
#pragma unroll
      for (int e = 0; e < 4; ++e) nv[e] = (vb[4*u+e] - mean) * rstd * gg[e] + bb[e];
      *(bf16x4*)&h_s[t * LDA + p * 24 + 4 * u] = __builtin_convertvector(nv, bf16x4);
    }
  }
  // no barrier: phase 2 reads only own-wave h rows

  // ---------------- Phase 2: QKV projection (B-frags direct from global) ----
  const float qscale = 0.17677669529663687f;  // 1/sqrt(32)
  const __bf16* fbase = ws + (size_t)lane * 8;
  const int rowb = 16 * wv;
  bf16x8 aq3[3];
#pragma unroll
  for (int c = 0; c < 3; ++c) {
    bf16x8 wf[6][3];
#pragma unroll
    for (int t = 0; t < 6; ++t)
#pragma unroll
      for (int ks = 0; ks < 3; ++ks)
        wf[t][ks] = *(const bf16x8*)(fbase + (size_t)(c * 18 + t * 3 + ks) * 512);
    f32x4 acc[6];
#pragma unroll
    for (int t = 0; t < 6; ++t) {
      const float bv = qkvb[c * 96 + t * 16 + l15];
      f32x4 a4 = {bv, bv, bv, bv};
      acc[t] = a4;
    }
#pragma unroll
    for (int ks = 0; ks < 3; ++ks) {
      bf16x8 a = *(const bf16x8*)&h_s[(rowb + l15) * LDA + ks * 32 + 8 * g4];
#pragma unroll
      for (int t = 0; t < 6; ++t)
        acc[t] = __builtin_amdgcn_mfma_f32_16x16x32_bf16(a, wf[t][ks], acc[t], 0, 0, 0);
    }
    if (c == 0) {
      // q: scatter into k_s as scratch (own rows), read back A-frags, then
      // c==1's k scatter overwrites (own rows only -> no cross-wave race).
#pragma unroll
      for (int t = 0; t < 6; ++t) {
        const int head = t >> 1, dim = (t & 1) * 16 + l15;
#pragma unroll
        for (int r = 0; r < 4; ++r)
          k_s[(head * 64 + rowb + 4 * g4 + r) * LDQ + dim] = (__bf16)(acc[t][r] * qscale);
      }
#pragma unroll
      for (int h = 0; h < 3; ++h)
        aq3[h] = *(const bf16x8*)&k_s[(h * 64 + rowb + l15) * LDQ + 8 * g4];
    } else if (c == 1) {
#pragma unroll
      for (int t = 0; t < 6; ++t) {
        const int head = t >> 1, dim = (t & 1) * 16 + l15;
#pragma unroll
        for (int r = 0; r < 4; ++r)
          k_s[(head * 64 + rowb + 4 * g4 + r) * LDQ + dim] = (__bf16)acc[t][r];
      }
    } else {  // v transposed [head][dim][tok]; 4 regs = 4 consecutive toks
#pragma unroll
      for (int t = 0; t < 6; ++t) {
        const int head = t >> 1, dim = (t & 1) * 16 + l15;
        *(bf16x4*)&v_s[(head * 32 + dim) * LDV + rowb + 4 * g4] =
            __builtin_convertvector(acc[t], bf16x4);
      }
    }
  }

  __syncthreads();   // the ONLY barrier: k_s/v_s visible; h region now dead

  // ---------------- Phase 3: attention, head by head ----------------
  int qry[4], qrx[4];
#pragma unroll
  for (int r = 0; r < 4; ++r) {
    const int row = rowb + 4 * g4 + r;
    const int ti2 = row >> 3, tj2 = row & 7;
    qry[r] = (wy == 15) ? (ti2 < 4 ? 1 : 2) : 0;
    qrx[r] = (wx == 15) ? (tj2 < 4 ? 1 : 2) : 0;
  }
  const f32x4 zf = {0.f, 0.f, 0.f, 0.f};
  f32x4 ovA[3][2];
#pragma unroll
  for (int h = 0; h < 3; ++h) {
    const float* bh = biasf + h * 4096;
    float bv[4][4];
#pragma unroll
    for (int n = 0; n < 4; ++n)
#pragma unroll
      for (int r = 0; r < 4; ++r)
        bv[n][r] = bh[(rowb + 4 * g4 + r) * 64 + n * 16 + l15];

    f32x4 sc[4];
#pragma unroll
    for (int n = 0; n < 4; ++n) {
      bf16x8 bk = *(const bf16x8*)&k_s[(h * 64 + n * 16 + l15) * LDQ + 8 * g4];
      sc[n] = __builtin_amdgcn_mfma_f32_16x16x32_bf16(aq3[h], bk, zf, 0, 0, 0);
    }
#pragma unroll
    for (int n = 0; n < 4; ++n) {
      const int colt = n * 16 + l15;
      const int ki = colt >> 3, kj = colt & 7;
      const int kry = (wy == 15) ? (ki < 4 ? 1 : 2) : 0;
      const int krx = (wx == 15) ? (kj < 4 ? 1 : 2) : 0;
#pragma unroll
      for (int r = 0; r < 4; ++r) {
        const float mk = (qry[r] == kry && qrx[r] == krx) ? 0.f : -100.f;
        sc[n][r] += bv[n][r] + mk;
      }
    }
    float mx[4], sm[4];
#pragma unroll
    for (int r = 0; r < 4; ++r) {
      float m = fmaxf(fmaxf(sc[0][r], sc[1][r]), fmaxf(sc[2][r], sc[3][r]));
      m = fmaxf(m, __shfl_xor(m, 1)); m = fmaxf(m, __shfl_xor(m, 2));
      m = fmaxf(m, __shfl_xor(m, 4)); m = fmaxf(m, __shfl_xor(m, 8));
      mx[r] = m; sm[r] = 0.f;
    }
#pragma unroll
    for (int n = 0; n < 4; ++n)
#pragma unroll
      for (int r = 0; r < 4; ++r) {
        float p = __expf(sc[n][r] - mx[r]); sc[n][r] = p; sm[r] += p;
      }
#pragma unroll
    for (int r = 0; r < 4; ++r) {
      float s2 = sm[r];
      s2 += __shfl_xor(s2, 1); s2 += __shfl_xor(s2, 2);
      s2 += __shfl_xor(s2, 4); s2 += __shfl_xor(s2, 8);
      sm[r] = __builtin_amdgcn_rcpf(s2);
    }
    // P -> h_s cols 0..63 (over dead h; wave-local rows)
#pragma unroll
    for (int n = 0; n < 4; ++n)
#pragma unroll
      for (int r = 0; r < 4; ++r)
        h_s[(rowb + 4 * g4 + r) * LDA + n * 16 + l15] = (__bf16)sc[n][r];
    f32x4 ov[2] = {zf, zf};
#pragma unroll
    for (int ks = 0; ks < 2; ++ks) {
      bf16x8 pa = *(const bf16x8*)&h_s[(rowb + l15) * LDA + ks * 32 + 8 * g4];
#pragma unroll
      for (int t2 = 0; t2 < 2; ++t2) {
        bf16x8 vb2 = *(const bf16x8*)&v_s[(h * 32 + t2 * 16 + l15) * LDV + ks * 32 + 8 * g4];
        ov[t2] = __builtin_amdgcn_mfma_f32_16x16x32_bf16(pa, vb2, ov[t2], 0, 0, 0);
      }
    }
#pragma unroll
    for (int t2 = 0; t2 < 2; ++t2)
#pragma unroll
      for (int r = 0; r < 4; ++r)
        ovA[h][t2][r] = ov[t2][r] * sm[r];
  }
  // flush attn-out to h_s (overwrites dead P; wave-local rows)
#pragma unroll
  for (int h = 0; h < 3; ++h)
#pragma unroll
    for (int t2 = 0; t2 < 2; ++t2)
#pragma unroll
      for (int r = 0; r < 4; ++r)
        h_s[(rowb + 4 * g4 + r) * LDA + h * 32 + t2 * 16 + l15] = (__bf16)ovA[h][t2][r];
  // no barrier: proj reads only own-wave rows

  // ---------------- Phase 4: output projection (B-frags direct) -------------
  f32x4 po[6];
#pragma unroll
  for (int t = 0; t < 6; ++t) po[t] = zf;
#pragma unroll
  for (int ks = 0; ks < 3; ++ks) {
    bf16x8 a = *(const bf16x8*)&h_s[(rowb + l15) * LDA + ks * 32 + 8 * g4];
#pragma unroll
    for (int t = 0; t < 6; ++t) {
      bf16x8 bb = *(const bf16x8*)(fbase + (size_t)(54 + t * 3 + ks) * 512);
      po[t] = __builtin_amdgcn_mfma_f32_16x16x32_bf16(a, bb, po[t], 0, 0, 0);
    }
  }
  // epilogue: window reverse + unshift + residual
#pragma unroll
  for (int r = 0; r < 4; ++r) {
    const int row = rowb + 4 * g4 + r;
    const int ti2 = row >> 3, tj2 = row & 7;
    const int iy = (wy * 8 + ti2 + SHIFT) & 127;
    const int ix = (wx * 8 + tj2 + SHIFT) & 127;
    const size_t gbase = ((size_t)(b * 16384 + iy * 128 + ix)) * 96;
#pragma unroll
    for (int t = 0; t < 6; ++t) {
      const size_t gi = gbase + t * 16 + l15;
      out[gi] = x[gi] + po[t][r];
    }
  }
}

// ---------------------------------------------------------------------------
// Kernel 2: LN2 + MLP(4x, gelu-tanh) + residual, in place on d_out.
// R4-proven structure: 512 threads, 128 rows, alternating single w buffer.
// ---------------------------------------------------------------------------
__global__ __launch_bounds__(512, 4)
void swin_mlp_kernel(const float* __restrict__ ln2g, const float* __restrict__ ln2b,
                     const __bf16* __restrict__ ws, float* xm)
{
  __shared__ __bf16 h_s[128][LDA];   // 26624 B
  __shared__ __bf16 u_s[128][LDA];   // 26624 B
  __shared__ __bf16 w_s[96][LDW];    // 19968 B (w1 chunk, then w2 chunk)

  const int tid = threadIdx.x, lane = tid & 63, wv = tid >> 6;
  const int l15 = lane & 15, g4 = lane >> 4;
  const size_t rowg = (size_t)blockIdx.x * 128;

  // LN2 (4 lanes per row)
  {
    const int t = tid >> 2, p = tid & 3;
    const float* rowp = xm + (rowg + t) * 96 + p * 24;
    float vb[24];
    float s = 0.f, ss = 0.f;
#pragma unroll
    for (int u = 0; u < 6; ++u) {
      f32x4 f = *(const f32x4*)(rowp + 4 * u);
#pragma unroll
      for (int e = 0; e < 4; ++e) { float q = f[e]; vb[4*u+e] = q; s += q; ss += q*q; }
    }
    s  += __shfl_xor(s, 1);  s  += __shfl_xor(s, 2);
    ss += __shfl_xor(ss, 1); ss += __shfl_xor(ss, 2);
    const float mean = s * (1.f / 96.f);
    const float var  = ss * (1.f / 96.f) - mean * mean;
    const float rstd = rsqrtf(var + 1e-5f);
#pragma unroll
    for (int u = 0; u < 6; ++u) {
      f32x4 gg = *(const f32x4*)(ln2g + p * 24 + 4 * u);
      f32x4 bb = *(const f32x4*)(ln2b + p * 24 + 4 * u);
      f32x4 nv;
#pragma unroll
      for (int e = 0; e < 4; ++e) nv[e] = (vb[4*u+e] - mean) * rstd * gg[e] + bb[e];
      *(bf16x4*)&h_s[t][p * 24 + 4 * u] = __builtin_convertvector(nv, bf16x4);
    }
  }
  __syncthreads();

  const int rowb = 16 * wv;
  const f32x4 zf = {0.f, 0.f, 0.f, 0.f};
  f32x4 acc[6];
#pragma unroll
  for (int t = 0; t < 6; ++t) acc[t] = zf;

  for (int c = 0; c < 4; ++c) {   // 4 chunks of 96 hidden cols
    {  // stage w1 chunk [96][96]
      const __bf16* wsrc = ws + WS_W1T + c * 9216;
      for (int m = tid; m < 1152; m += 512) {
        const int row = m / 12, q4 = m - row * 12;
        *(uint4*)&w_s[row][q4 * 8] = *(const uint4*)&wsrc[row * 96 + q4 * 8];
      }
    }
    __syncthreads();
    f32x4 ua[6];
#pragma unroll
    for (int t = 0; t < 6; ++t) ua[t] = zf;
#pragma unroll
    for (int ks = 0; ks < 3; ++ks) {
      bf16x8 a = *(const bf16x8*)&h_s[rowb + l15][ks * 32 + 8 * g4];
#pragma unroll
      for (int t = 0; t < 6; ++t) {
        bf16x8 bb = *(const bf16x8*)&w_s[t * 16 + l15][ks * 32 + 8 * g4];
        ua[t] = __builtin_amdgcn_mfma_f32_16x16x32_bf16(a, bb, ua[t], 0, 0, 0);
      }
    }
    // gelu -> u_s (wave-local rows)
#pragma unroll
    for (int t = 0; t < 6; ++t)
#pragma unroll
      for (int r = 0; r < 4; ++r) {
        const float v = ua[t][r];
        const float a3 = 0.7978845608028654f * (v + 0.044715f * v * v * v);
        const float e = __expf(2.f * a3);
        const float g = v - v * __builtin_amdgcn_rcpf(e + 1.f);
        u_s[rowb + 4 * g4 + r][t * 16 + l15] = (__bf16)g;
      }
    __syncthreads();   // all waves done reading w1 chunk
    {  // stage w2 chunk [96][96]
      const __bf16* wsrc = ws + WS_W2C + c * 9216;
      for (int m = tid; m < 1152; m += 512) {
        const int row = m / 12, q4 = m - row * 12;
        *(uint4*)&w_s[row][q4 * 8] = *(const uint4*)&wsrc[row * 96 + q4 * 8];
      }
    }
    __syncthreads();
#pragma unroll
    for (int ks = 0; ks < 3; ++ks) {
      bf16x8 pa = *(const bf16x8*)&u_s[rowb + l15][ks * 32 + 8 * g4];
#pragma unroll
      for (int t = 0; t < 6; ++t) {
        bf16x8 bb = *(const bf16x8*)&w_s[t * 16 + l15][ks * 32 + 8 * g4];
        acc[t] = __builtin_amdgcn_mfma_f32_16x16x32_bf16(pa, bb, acc[t], 0, 0, 0);
      }
    }
    __syncthreads();   // weight buffer reusable next chunk
  }
  // epilogue: residual, in place (rows owned by this wave only)
#pragma unroll
  for (int r = 0; r < 4; ++r) {
    const size_t gr = (rowg + rowb + 4 * g4 + r) * 96;
#pragma unroll
    for (int t = 0; t < 6; ++t) {
      const size_t gi = gr + t * 16 + l15;
      xm[gi] = xm[gi] + acc[t][r];
    }
  }
}

extern "C" void kernel_launch(void* const* d_in, const int* in_sizes, int n_in,
                              void* d_out, int out_size, void* d_ws, size_t ws_size,
                              hipStream_t stream) {
  (void)in_sizes; (void)n_in; (void)out_size; (void)ws_size;
  const float* x     = (const float*)d_in[0];
  const float* ln1g  = (const float*)d_in[1];
  const float* ln1b  = (const float*)d_in[2];
  const float* qkvw  = (const float*)d_in[3];
  const float* qkvb  = (const float*)d_in[4];
  const float* projw = (const float*)d_in[5];
  const float* btab  = (const float*)d_in[6];
  const float* ln2g  = (const float*)d_in[7];
  const float* ln2b  = (const float*)d_in[8];
  const float* w1    = (const float*)d_in[9];
  const float* w2    = (const float*)d_in[10];
  float* out = (float*)d_out;
  __bf16* ws = (__bf16*)d_ws;

  // 122880 items = 110592 weight elems + 12288 bias elems
  swin_prep_kernel<<<480, 256, 0, stream>>>(qkvw, projw, w1, w2, btab, ws);
  swin_attn_kernel<<<4096, 256, 0, stream>>>(x, ln1g, ln1b, ws, qkvb, out);
  swin_mlp_kernel<<<2048, 512, 0, stream>>>(ln2g, ln2b, ws, out);
}

// Round 9
// 189.377 us; speedup vs baseline: 1.2127x; 1.0395x over previous
//
#include <hip/hip_runtime.h>

#define SHIFT 4

typedef __bf16 bf16x8 __attribute__((ext_vector_type(8)));
typedef __bf16 bf16x4 __attribute__((ext_vector_type(4)));
typedef float  f32x4  __attribute__((ext_vector_type(4)));

// ws layout (bf16 elements unless noted):
//   frag region @ 0     : 72 frags x 512 (qkv c*18+t*3+ks: 0..53; proj 54+t*3+ks)
//                         lane L holds 8 contraction vals for the MFMA B-frag
//   w1T         @ 36864 : [384 outcols][96 k]           (64-row chunks contiguous)
//   w2C         @ 73728 : [6 chunks][96 outcols][64 j]
//   bias f32    @ byte 221184 : [3][64][64] full rel-pos bias
#define WS_W1T  36864
#define WS_W2C  73728
#define WS_BIAS_BYTES 221184

// ---------------------------------------------------------------------------
// Kernel 0: weight prep + full rel-pos bias tensor.
// ---------------------------------------------------------------------------
__global__ __launch_bounds__(256)
void swin_prep_kernel(const float* __restrict__ qkvw, const float* __restrict__ projw,
                      const float* __restrict__ w1, const float* __restrict__ w2,
                      const float* __restrict__ btab,
                      __bf16* __restrict__ ws)
{
  const int i = blockIdx.x * 256 + threadIdx.x;
  if (i < 36864) {                       // fragment-ordered qkv + proj
    const int fi = i >> 9, e = i & 511;
    const int lane = e >> 3, j = e & 7;
    const int l15 = lane & 15;
    const int kk  = (lane >> 4) * 8 + j;
    float v;
    if (fi < 54) {                       // qkvw [96][288]
      const int c = fi / 18, rem = fi % 18, t = rem / 3, ks = rem % 3;
      v = qkvw[(ks * 32 + kk) * 288 + c * 96 + t * 16 + l15];
    } else {                             // projw [96][96]
      const int f2 = fi - 54, t = f2 / 3, ks = f2 % 3;
      v = projw[(ks * 32 + kk) * 96 + t * 16 + l15];
    }
    ws[i] = (__bf16)v;
  } else if (i < 73728) {                // w1T [384][96]; w1 is [96][384]
    const int j = i - WS_W1T;
    const int col = j / 96, kk = j - col * 96;
    ws[i] = (__bf16)w1[kk * 384 + col];
  } else if (i < 110592) {               // w2C [6][96][64]; w2 is [384][96]
    const int j = i - WS_W2C;
    const int cc = j / 6144, r2 = j - cc * 6144;
    const int o = r2 / 64, jl = r2 - o * 64;
    ws[i] = (__bf16)w2[(cc * 64 + jl) * 96 + o];
  } else {                               // bias_full[h][n][m]
    const int jj = i - 110592;           // < 12288
    const int h = jj >> 12, n = (jj >> 6) & 63, m = jj & 63;
    const int dy = (n >> 3) - (m >> 3), dx = (n & 7) - (m & 7);
    float* biasf = (float*)((char*)ws + WS_BIAS_BYTES);
    biasf[jj] = btab[((dy + 7) * 15 + (dx + 7)) * 3 + h];
  }
}

// ---------------------------------------------------------------------------
// Kernel 1: LN1 + shift/partition + MHSA + proj + residual.
// LDS 40448 B -> 4 blocks/CU. k packed [64 tok][96 dim] (q-scratch same
// region); P aliases dead h region; attn-out in regs. One barrier total.
// ---------------------------------------------------------------------------
#define LDA 104   // h rows (and packed k rows): 208 B, 16B-mult
#define LDV 72    // v transposed rows: 144 B

__global__ __launch_bounds__(256, 4)
void swin_attn_kernel(const float* __restrict__ x,
                      const float* __restrict__ ln1g, const float* __restrict__ ln1b,
                      const __bf16* __restrict__ ws, const float* __restrict__ qkvb,
                      float* __restrict__ out)
{
  __shared__ __align__(16) char lds[40448];
  __bf16* h_s = (__bf16*)lds;              // [64][LDA]   13312 B (h, P, attn-out)
  __bf16* k_s = (__bf16*)(lds + 13312);    // [64][LDA]   13312 B (q-scratch, then k; col = head*32+dim)
  __bf16* v_s = (__bf16*)(lds + 26624);    // [3][32][LDV] 13824 B

  const float* biasf = (const float*)((const char*)ws + WS_BIAS_BYTES);

  const int tid  = threadIdx.x;
  const int lane = tid & 63;
  const int wv   = tid >> 6;
  const int l15  = lane & 15;
  const int g4   = lane >> 4;
  const int blk  = blockIdx.x;          // b*256 + wy*16 + wx
  const int b    = blk >> 8;
  const int wy   = (blk >> 4) & 15;
  const int wx   = blk & 15;

  // ---------------- Phase 1: LayerNorm1 (4 lanes/token; wave-local rows) ----
  {
    const int t = tid >> 2, p = tid & 3;
    const int ti = t >> 3, tj = t & 7;
    const int iy = (wy * 8 + ti + SHIFT) & 127;
    const int ix = (wx * 8 + tj + SHIFT) & 127;
    const float* rowp = x + ((size_t)(b * 16384 + iy * 128 + ix)) * 96 + p * 24;
    float vb[24];
    float s = 0.f, ss = 0.f;
#pragma unroll
    for (int u = 0; u < 6; ++u) {
      f32x4 f = *(const f32x4*)(rowp + 4 * u);
#pragma unroll
      for (int e = 0; e < 4; ++e) { float q = f[e]; vb[4*u+e] = q; s += q; ss += q*q; }
    }
    s  += __shfl_xor(s, 1);  s  += __shfl_xor(s, 2);
    ss += __shfl_xor(ss, 1); ss += __shfl_xor(ss, 2);
    const float mean = s * (1.f / 96.f);
    const float var  = ss * (1.f / 96.f) - mean * mean;
    const float rstd = rsqrtf(var + 1e-5f);
#pragma unroll
    for (int u = 0; u < 6; ++u) {
      f32x4 gg = *(const f32x4*)(ln1g + p * 24 + 4 * u);
      f32x4 bb = *(const f32x4*)(ln1b + p * 24 + 4 * u);
      f32x4 nv;
#pragma unroll
      for (int e = 0; e < 4; ++e) nv[e] = (vb[4*u+e] - mean) * rstd * gg[e] + bb[e];
      *(bf16x4*)&h_s[t * LDA + p * 24 + 4 * u] = __builtin_convertvector(nv, bf16x4);
    }
  }
  // no barrier: phase 2 reads only own-wave h rows

  // ---------------- Phase 2: QKV projection (B-frags direct from global) ----
  const float qscale = 0.17677669529663687f;  // 1/sqrt(32)
  const __bf16* fbase = ws + (size_t)lane * 8;
  const int rowb = 16 * wv;
  bf16x8 aq3[3];
#pragma unroll
  for (int c = 0; c < 3; ++c) {
    bf16x8 wf[6][3];
#pragma unroll
    for (int t = 0; t < 6; ++t)
#pragma unroll
      for (int ks = 0; ks < 3; ++ks)
        wf[t][ks] = *(const bf16x8*)(fbase + (size_t)(c * 18 + t * 3 + ks) * 512);
    f32x4 acc[6];
#pragma unroll
    for (int t = 0; t < 6; ++t) {
      const float bv = qkvb[c * 96 + t * 16 + l15];
      f32x4 a4 = {bv, bv, bv, bv};
      acc[t] = a4;
    }
#pragma unroll
    for (int ks = 0; ks < 3; ++ks) {
      bf16x8 a = *(const bf16x8*)&h_s[(rowb + l15) * LDA + ks * 32 + 8 * g4];
#pragma unroll
      for (int t = 0; t < 6; ++t)
        acc[t] = __builtin_amdgcn_mfma_f32_16x16x32_bf16(a, wf[t][ks], acc[t], 0, 0, 0);
    }
    if (c == 0) {
      // q: scatter into k_s as scratch (own rows), read back A-frags; c==1's
      // k scatter overwrites same own rows -> no cross-wave race.
#pragma unroll
      for (int t = 0; t < 6; ++t) {
        const int col = (t >> 1) * 32 + (t & 1) * 16 + l15;   // head*32 + dim
#pragma unroll
        for (int r = 0; r < 4; ++r)
          k_s[(rowb + 4 * g4 + r) * LDA + col] = (__bf16)(acc[t][r] * qscale);
      }
#pragma unroll
      for (int h = 0; h < 3; ++h)
        aq3[h] = *(const bf16x8*)&k_s[(rowb + l15) * LDA + h * 32 + 8 * g4];
    } else if (c == 1) {
#pragma unroll
      for (int t = 0; t < 6; ++t) {
        const int col = (t >> 1) * 32 + (t & 1) * 16 + l15;
#pragma unroll
        for (int r = 0; r < 4; ++r)
          k_s[(rowb + 4 * g4 + r) * LDA + col] = (__bf16)acc[t][r];
      }
    } else {  // v transposed [head][dim][tok]; 4 regs = 4 consecutive toks
#pragma unroll
      for (int t = 0; t < 6; ++t) {
        const int head = t >> 1, dim = (t & 1) * 16 + l15;
        *(bf16x4*)&v_s[(head * 32 + dim) * LDV + rowb + 4 * g4] =
            __builtin_convertvector(acc[t], bf16x4);
      }
    }
  }

  __syncthreads();   // the ONLY barrier: k_s/v_s visible; h region now dead

  // ---------------- Phase 3: attention, head by head ----------------
  int qry[4], qrx[4];
#pragma unroll
  for (int r = 0; r < 4; ++r) {
    const int row = rowb + 4 * g4 + r;
    const int ti2 = row >> 3, tj2 = row & 7;
    qry[r] = (wy == 15) ? (ti2 < 4 ? 1 : 2) : 0;
    qrx[r] = (wx == 15) ? (tj2 < 4 ? 1 : 2) : 0;
  }
  const f32x4 zf = {0.f, 0.f, 0.f, 0.f};
  f32x4 ovA[3][2];
#pragma unroll
  for (int h = 0; h < 3; ++h) {
    const float* bh = biasf + h * 4096;
    float bv[4][4];
#pragma unroll
    for (int n = 0; n < 4; ++n)
#pragma unroll
      for (int r = 0; r < 4; ++r)
        bv[n][r] = bh[(rowb + 4 * g4 + r) * 64 + n * 16 + l15];

    f32x4 sc[4];
#pragma unroll
    for (int n = 0; n < 4; ++n) {
      bf16x8 bk = *(const bf16x8*)&k_s[(n * 16 + l15) * LDA + h * 32 + 8 * g4];
      sc[n] = __builtin_amdgcn_mfma_f32_16x16x32_bf16(aq3[h], bk, zf, 0, 0, 0);
    }
#pragma unroll
    for (int n = 0; n < 4; ++n) {
      const int colt = n * 16 + l15;
      const int ki = colt >> 3, kj = colt & 7;
      const int kry = (wy == 15) ? (ki < 4 ? 1 : 2) : 0;
      const int krx = (wx == 15) ? (kj < 4 ? 1 : 2) : 0;
#pragma unroll
      for (int r = 0; r < 4; ++r) {
        const float mk = (qry[r] == kry && qrx[r] == krx) ? 0.f : -100.f;
        sc[n][r] += bv[n][r] + mk;
      }
    }
    float mx[4], sm[4];
#pragma unroll
    for (int r = 0; r < 4; ++r) {
      float m = fmaxf(fmaxf(sc[0][r], sc[1][r]), fmaxf(sc[2][r], sc[3][r]));
      m = fmaxf(m, __shfl_xor(m, 1)); m = fmaxf(m, __shfl_xor(m, 2));
      m = fmaxf(m, __shfl_xor(m, 4)); m = fmaxf(m, __shfl_xor(m, 8));
      mx[r] = m; sm[r] = 0.f;
    }
#pragma unroll
    for (int n = 0; n < 4; ++n)
#pragma unroll
      for (int r = 0; r < 4; ++r) {
        float p = __expf(sc[n][r] - mx[r]); sc[n][r] = p; sm[r] += p;
      }
#pragma unroll
    for (int r = 0; r < 4; ++r) {
      float s2 = sm[r];
      s2 += __shfl_xor(s2, 1); s2 += __shfl_xor(s2, 2);
      s2 += __shfl_xor(s2, 4); s2 += __shfl_xor(s2, 8);
      sm[r] = __builtin_amdgcn_rcpf(s2);
    }
    // P -> h_s cols 0..63 (over dead h; wave-local rows)
#pragma unroll
    for (int n = 0; n < 4; ++n)
#pragma unroll
      for (int r = 0; r < 4; ++r)
        h_s[(rowb + 4 * g4 + r) * LDA + n * 16 + l15] = (__bf16)sc[n][r];
    f32x4 ov[2] = {zf, zf};
#pragma unroll
    for (int ks = 0; ks < 2; ++ks) {
      bf16x8 pa = *(const bf16x8*)&h_s[(rowb + l15) * LDA + ks * 32 + 8 * g4];
#pragma unroll
      for (int t2 = 0; t2 < 2; ++t2) {
        bf16x8 vb2 = *(const bf16x8*)&v_s[(h * 32 + t2 * 16 + l15) * LDV + ks * 32 + 8 * g4];
        ov[t2] = __builtin_amdgcn_mfma_f32_16x16x32_bf16(pa, vb2, ov[t2], 0, 0, 0);
      }
    }
#pragma unroll
    for (int t2 = 0; t2 < 2; ++t2)
#pragma unroll
      for (int r = 0; r < 4; ++r)
        ovA[h][t2][r] = ov[t2][r] * sm[r];
  }
  // flush attn-out to h_s (overwrites dead P; wave-local rows)
#pragma unroll
  for (int h = 0; h < 3; ++h)
#pragma unroll
    for (int t2 = 0; t2 < 2; ++t2)
#pragma unroll
      for (int r = 0; r < 4; ++r)
        h_s[(rowb + 4 * g4 + r) * LDA + h * 32 + t2 * 16 + l15] = (__bf16)ovA[h][t2][r];
  // no barrier: proj reads only own-wave rows

  // ---------------- Phase 4: output projection (B-frags direct) -------------
  f32x4 po[6];
#pragma unroll
  for (int t = 0; t < 6; ++t) po[t] = zf;
#pragma unroll
  for (int ks = 0; ks < 3; ++ks) {
    bf16x8 a = *(const bf16x8*)&h_s[(rowb + l15) * LDA + ks * 32 + 8 * g4];
#pragma unroll
    for (int t = 0; t < 6; ++t) {
      bf16x8 bb = *(const bf16x8*)(fbase + (size_t)(54 + t * 3 + ks) * 512);
      po[t] = __builtin_amdgcn_mfma_f32_16x16x32_bf16(a, bb, po[t], 0, 0, 0);
    }
  }
  // epilogue: window reverse + unshift + residual
#pragma unroll
  for (int r = 0; r < 4; ++r) {
    const int row = rowb + 4 * g4 + r;
    const int ti2 = row >> 3, tj2 = row & 7;
    const int iy = (wy * 8 + ti2 + SHIFT) & 127;
    const int ix = (wx * 8 + tj2 + SHIFT) & 127;
    const size_t gbase = ((size_t)(b * 16384 + iy * 128 + ix)) * 96;
#pragma unroll
    for (int t = 0; t < 6; ++t) {
      const size_t gi = gbase + t * 16 + l15;
      out[gi] = x[gi] + po[t][r];
    }
  }
}

// ---------------------------------------------------------------------------
// Kernel 2: LN2 + MLP(4x, gelu-tanh) + residual, in place on d_out.
// 256 threads / 64 rows / 64-col hidden chunks; LDS 36352 B -> 4 blocks/CU.
// ---------------------------------------------------------------------------
#define LDH 104   // h rows
#define LDU 72    // u rows (64 cols used)
#define LDW1 104  // w1 chunk rows: [64 outcols][96 k]
#define LDW2 72   // w2 chunk rows: [96 outcols][64 j]

__global__ __launch_bounds__(256, 4)
void swin_mlp_kernel(const float* __restrict__ ln2g, const float* __restrict__ ln2b,
                     const __bf16* __restrict__ ws, float* xm)
{
  __shared__ __align__(16) char mlds[36352];
  __bf16* h_s = (__bf16*)mlds;             // [64][LDH]  13312 B
  __bf16* u_s = (__bf16*)(mlds + 13312);   // [64][LDU]   9216 B
  __bf16* w_s = (__bf16*)(mlds + 22528);   // 13824 B: w1 [64][LDW1] / w2 [96][LDW2]

  const int tid = threadIdx.x, lane = tid & 63, wv = tid >> 6;
  const int l15 = lane & 15, g4 = lane >> 4;
  const size_t rowg = (size_t)blockIdx.x * 64;

  // LN2 (4 lanes per row; wave-local rows)
  {
    const int t = tid >> 2, p = tid & 3;
    const float* rowp = xm + (rowg + t) * 96 + p * 24;
    float vb[24];
    float s = 0.f, ss = 0.f;
#pragma unroll
    for (int u = 0; u < 6; ++u) {
      f32x4 f = *(const f32x4*)(rowp + 4 * u);
#pragma unroll
      for (int e = 0; e < 4; ++e) { float q = f[e]; vb[4*u+e] = q; s += q; ss += q*q; }
    }
    s  += __shfl_xor(s, 1);  s  += __shfl_xor(s, 2);
    ss += __shfl_xor(ss, 1); ss += __shfl_xor(ss, 2);
    const float mean = s * (1.f / 96.f);
    const float var  = ss * (1.f / 96.f) - mean * mean;
    const float rstd = rsqrtf(var + 1e-5f);
#pragma unroll
    for (int u = 0; u < 6; ++u) {
      f32x4 gg = *(const f32x4*)(ln2g + p * 24 + 4 * u);
      f32x4 bb = *(const f32x4*)(ln2b + p * 24 + 4 * u);
      f32x4 nv;
#pragma unroll
      for (int e = 0; e < 4; ++e) nv[e] = (vb[4*u+e] - mean) * rstd * gg[e] + bb[e];
      *(bf16x4*)&h_s[t * LDH + p * 24 + 4 * u] = __builtin_convertvector(nv, bf16x4);
    }
  }
  __syncthreads();

  const int rowb = 16 * wv;
  const f32x4 zf = {0.f, 0.f, 0.f, 0.f};
  f32x4 acc[6];
#pragma unroll
  for (int t = 0; t < 6; ++t) acc[t] = zf;

  for (int cc = 0; cc < 6; ++cc) {   // 6 chunks of 64 hidden cols
    {  // stage w1 chunk [64 outcols][96 k]
      const __bf16* wsrc = ws + WS_W1T + cc * 6144;
#pragma unroll
      for (int m = tid; m < 768; m += 256) {
        const int row = m / 12, q4 = m - row * 12;
        *(uint4*)&w_s[row * LDW1 + q4 * 8] = *(const uint4*)&wsrc[row * 96 + q4 * 8];
      }
    }
    __syncthreads();
    f32x4 ua[4];
#pragma unroll
    for (int t = 0; t < 4; ++t) ua[t] = zf;
#pragma unroll
    for (int ks = 0; ks < 3; ++ks) {
      bf16x8 a = *(const bf16x8*)&h_s[(rowb + l15) * LDH + ks * 32 + 8 * g4];
#pragma unroll
      for (int t = 0; t < 4; ++t) {
        bf16x8 bb = *(const bf16x8*)&w_s[(t * 16 + l15) * LDW1 + ks * 32 + 8 * g4];
        ua[t] = __builtin_amdgcn_mfma_f32_16x16x32_bf16(a, bb, ua[t], 0, 0, 0);
      }
    }
    // gelu -> u_s (wave-local rows)
#pragma unroll
    for (int t = 0; t < 4; ++t)
#pragma unroll
      for (int r = 0; r < 4; ++r) {
        const float v = ua[t][r];
        const float e = __expf(1.5957691216057308f * (v + 0.044715f * v * v * v));
        const float g = v - v * __builtin_amdgcn_rcpf(e + 1.f);
        u_s[(rowb + 4 * g4 + r) * LDU + t * 16 + l15] = (__bf16)g;
      }
    __syncthreads();   // all waves done reading w1 chunk
    {  // stage w2 chunk [96 outcols][64 j]
      const __bf16* wsrc = ws + WS_W2C + cc * 6144;
#pragma unroll
      for (int m = tid; m < 768; m += 256) {
        const int row = m >> 3, q4 = m & 7;
        *(uint4*)&w_s[row * LDW2 + q4 * 8] = *(const uint4*)&wsrc[row * 64 + q4 * 8];
      }
    }
    __syncthreads();
#pragma unroll
    for (int ks = 0; ks < 2; ++ks) {
      bf16x8 pa = *(const bf16x8*)&u_s[(rowb + l15) * LDU + ks * 32 + 8 * g4];
#pragma unroll
      for (int t = 0; t < 6; ++t) {
        bf16x8 bb = *(const bf16x8*)&w_s[(t * 16 + l15) * LDW2 + ks * 32 + 8 * g4];
        acc[t] = __builtin_amdgcn_mfma_f32_16x16x32_bf16(pa, bb, acc[t], 0, 0, 0);
      }
    }
    __syncthreads();   // w buffer reusable next chunk
  }
  // epilogue: residual, in place (rows owned by this wave only)
#pragma unroll
  for (int r = 0; r < 4; ++r) {
    const size_t gr = (rowg + rowb + 4 * g4 + r) * 96;
#pragma unroll
    for (int t = 0; t < 6; ++t) {
      const size_t gi = gr + t * 16 + l15;
      xm[gi] = xm[gi] + acc[t][r];
    }
  }
}

extern "C" void kernel_launch(void* const* d_in, const int* in_sizes, int n_in,
                              void* d_out, int out_size, void* d_ws, size_t ws_size,
                              hipStream_t stream) {
  (void)in_sizes; (void)n_in; (void)out_size; (void)ws_size;
  const float* x     = (const float*)d_in[0];
  const float* ln1g  = (const float*)d_in[1];
  const float* ln1b  = (const float*)d_in[2];
  const float* qkvw  = (const float*)d_in[3];
  const float* qkvb  = (const float*)d_in[4];
  const float* projw = (const float*)d_in[5];
  const float* btab  = (const float*)d_in[6];
  const float* ln2g  = (const float*)d_in[7];
  const float* ln2b  = (const float*)d_in[8];
  const float* w1    = (const float*)d_in[9];
  const float* w2    = (const float*)d_in[10];
  float* out = (float*)d_out;
  __bf16* ws = (__bf16*)d_ws;

  // 122880 items = 110592 weight elems + 12288 bias elems
  swin_prep_kernel<<<480, 256, 0, stream>>>(qkvw, projw, w1, w2, btab, ws);
  swin_attn_kernel<<<4096, 256, 0, stream>>>(x, ln1g, ln1b, ws, qkvb, out);
  swin_mlp_kernel<<<4096, 256, 0, stream>>>(ln2g, ln2b, ws, out);
}

// Round 10
// 166.606 us; speedup vs baseline: 1.3784x; 1.1367x over previous
//
#include <hip/hip_runtime.h>

#define SHIFT 4

typedef __bf16 bf16x8 __attribute__((ext_vector_type(8)));
typedef __bf16 bf16x4 __attribute__((ext_vector_type(4)));
typedef float  f32x4  __attribute__((ext_vector_type(4)));

// LDS leading dims (elements).
#define LDA 104   // h rows (and packed k rows)
#define LDV 72    // v transposed rows
#define LDU 72    // u rows (MLP, 64 cols used)
#define LDW1 104  // w1 chunk rows: [64 outcols][96 k]
#define LDW2 72   // w2 chunk rows: [96 outcols][64 j]

// ws layout (bf16 elements unless noted):
//   frag region @ 0     : 72 frags x 512 (qkv c*18+t*3+ks: 0..53; proj 54+t*3+ks)
//   w1T         @ 36864 : [384 outcols][96 k]      (64-row chunks contiguous)
//   w2C         @ 73728 : [6 chunks][96 outcols][64 j]
//   bias f32    @ byte 221184 : [3][64][64] full rel-pos bias
#define WS_W1T  36864
#define WS_W2C  73728
#define WS_BIAS_BYTES 221184

// ---------------------------------------------------------------------------
// Kernel 0: weight prep + full rel-pos bias tensor (identical to R9).
// ---------------------------------------------------------------------------
__global__ __launch_bounds__(256)
void swin_prep_kernel(const float* __restrict__ qkvw, const float* __restrict__ projw,
                      const float* __restrict__ w1, const float* __restrict__ w2,
                      const float* __restrict__ btab,
                      __bf16* __restrict__ ws)
{
  const int i = blockIdx.x * 256 + threadIdx.x;
  if (i < 36864) {                       // fragment-ordered qkv + proj
    const int fi = i >> 9, e = i & 511;
    const int lane = e >> 3, j = e & 7;
    const int l15 = lane & 15;
    const int kk  = (lane >> 4) * 8 + j;
    float v;
    if (fi < 54) {                       // qkvw [96][288]
      const int c = fi / 18, rem = fi % 18, t = rem / 3, ks = rem % 3;
      v = qkvw[(ks * 32 + kk) * 288 + c * 96 + t * 16 + l15];
    } else {                             // projw [96][96]
      const int f2 = fi - 54, t = f2 / 3, ks = f2 % 3;
      v = projw[(ks * 32 + kk) * 96 + t * 16 + l15];
    }
    ws[i] = (__bf16)v;
  } else if (i < 73728) {                // w1T [384][96]; w1 is [96][384]
    const int j = i - WS_W1T;
    const int col = j / 96, kk = j - col * 96;
    ws[i] = (__bf16)w1[kk * 384 + col];
  } else if (i < 110592) {               // w2C [6][96][64]; w2 is [384][96]
    const int j = i - WS_W2C;
    const int cc = j / 6144, r2 = j - cc * 6144;
    const int o = r2 / 64, jl = r2 - o * 64;
    ws[i] = (__bf16)w2[(cc * 64 + jl) * 96 + o];
  } else {                               // bias_full[h][n][m]
    const int jj = i - 110592;           // < 12288
    const int h = jj >> 12, n = (jj >> 6) & 63, m = jj & 63;
    const int dy = (n >> 3) - (m >> 3), dx = (n & 7) - (m & 7);
    float* biasf = (float*)((char*)ws + WS_BIAS_BYTES);
    biasf[jj] = btab[((dy + 7) * 15 + (dx + 7)) * 3 + h];
  }
}

// ---------------------------------------------------------------------------
// Fused kernel: LN1 + shift/partition + MHSA + proj + residual + LN2 (regs)
// + MLP + residual. One block per 8x8 window, 256 threads = 4 waves; wave wv
// owns rows 16wv..16wv+15 end-to-end. LDS 40448 B -> 4 blocks/CU.
// Attn phase: h | k(packed, q-scratch first) | v.  MLP phase (after barrier):
// u aliases k-region, w-chunk buffer aliases v-region.
// ---------------------------------------------------------------------------
__global__ __launch_bounds__(256, 4)
void swin_block_kernel(const float* __restrict__ x,
                       const float* __restrict__ ln1g, const float* __restrict__ ln1b,
                       const __bf16* __restrict__ ws, const float* __restrict__ qkvb,
                       const float* __restrict__ ln2g, const float* __restrict__ ln2b,
                       float* __restrict__ out)
{
  __shared__ __align__(16) char lds[40448];
  __bf16* h_s = (__bf16*)lds;              // [64][LDA]    13312 B (h, P, attn-out, h2)
  __bf16* k_s = (__bf16*)(lds + 13312);    // [64][LDA]    13312 B (q-scratch, then k)
  __bf16* v_s = (__bf16*)(lds + 26624);    // [3][32][LDV] 13824 B
  __bf16* u_s = (__bf16*)(lds + 13312);    // MLP: [64][LDU] 9216 B (aliases k_s)
  __bf16* w_s = (__bf16*)(lds + 26624);    // MLP: w1c [64][LDW1] / w2c [96][LDW2]

  const float* biasf = (const float*)((const char*)ws + WS_BIAS_BYTES);

  const int tid  = threadIdx.x;
  const int lane = tid & 63;
  const int wv   = tid >> 6;
  const int l15  = lane & 15;
  const int g4   = lane >> 4;
  const int blk  = blockIdx.x;          // b*256 + wy*16 + wx
  const int b    = blk >> 8;
  const int wy   = (blk >> 4) & 15;
  const int wx   = blk & 15;

  // ---------------- Phase 1: LayerNorm1 (4 lanes/token; wave-local rows) ----
  {
    const int t = tid >> 2, p = tid & 3;
    const int ti = t >> 3, tj = t & 7;
    const int iy = (wy * 8 + ti + SHIFT) & 127;
    const int ix = (wx * 8 + tj + SHIFT) & 127;
    const float* rowp = x + ((size_t)(b * 16384 + iy * 128 + ix)) * 96 + p * 24;
    float vb[24];
    float s = 0.f, ss = 0.f;
#pragma unroll
    for (int u = 0; u < 6; ++u) {
      f32x4 f = *(const f32x4*)(rowp + 4 * u);
#pragma unroll
      for (int e = 0; e < 4; ++e) { float q = f[e]; vb[4*u+e] = q; s += q; ss += q*q; }
    }
    s  += __shfl_xor(s, 1);  s  += __shfl_xor(s, 2);
    ss += __shfl_xor(ss, 1); ss += __shfl_xor(ss, 2);
    const float mean = s * (1.f / 96.f);
    const float var  = ss * (1.f / 96.f) - mean * mean;
    const float rstd = rsqrtf(var + 1e-5f);
#pragma unroll
    for (int u = 0; u < 6; ++u) {
      f32x4 gg = *(const f32x4*)(ln1g + p * 24 + 4 * u);
      f32x4 bb = *(const f32x4*)(ln1b + p * 24 + 4 * u);
      f32x4 nv;
#pragma unroll
      for (int e = 0; e < 4; ++e) nv[e] = (vb[4*u+e] - mean) * rstd * gg[e] + bb[e];
      *(bf16x4*)&h_s[t * LDA + p * 24 + 4 * u] = __builtin_convertvector(nv, bf16x4);
    }
  }
  // no barrier: phase 2 reads only own-wave h rows

  // ---------------- Phase 2: QKV projection (B-frags direct from global) ----
  const float qscale = 0.17677669529663687f;  // 1/sqrt(32)
  const __bf16* fbase = ws + (size_t)lane * 8;
  const int rowb = 16 * wv;
  bf16x8 aq3[3];
#pragma unroll
  for (int c = 0; c < 3; ++c) {
    bf16x8 wf[6][3];
#pragma unroll
    for (int t = 0; t < 6; ++t)
#pragma unroll
      for (int ks = 0; ks < 3; ++ks)
        wf[t][ks] = *(const bf16x8*)(fbase + (size_t)(c * 18 + t * 3 + ks) * 512);
    f32x4 acc[6];
#pragma unroll
    for (int t = 0; t < 6; ++t) {
      const float bv = qkvb[c * 96 + t * 16 + l15];
      f32x4 a4 = {bv, bv, bv, bv};
      acc[t] = a4;
    }
#pragma unroll
    for (int ks = 0; ks < 3; ++ks) {
      bf16x8 a = *(const bf16x8*)&h_s[(rowb + l15) * LDA + ks * 32 + 8 * g4];
#pragma unroll
      for (int t = 0; t < 6; ++t)
        acc[t] = __builtin_amdgcn_mfma_f32_16x16x32_bf16(a, wf[t][ks], acc[t], 0, 0, 0);
    }
    if (c == 0) {
      // q: scatter into k_s as scratch (own rows), read back A-frags; c==1's
      // k scatter overwrites same own rows -> no cross-wave race.
#pragma unroll
      for (int t = 0; t < 6; ++t) {
        const int col = (t >> 1) * 32 + (t & 1) * 16 + l15;   // head*32 + dim
#pragma unroll
        for (int r = 0; r < 4; ++r)
          k_s[(rowb + 4 * g4 + r) * LDA + col] = (__bf16)(acc[t][r] * qscale);
      }
#pragma unroll
      for (int h = 0; h < 3; ++h)
        aq3[h] = *(const bf16x8*)&k_s[(rowb + l15) * LDA + h * 32 + 8 * g4];
    } else if (c == 1) {
#pragma unroll
      for (int t = 0; t < 6; ++t) {
        const int col = (t >> 1) * 32 + (t & 1) * 16 + l15;
#pragma unroll
        for (int r = 0; r < 4; ++r)
          k_s[(rowb + 4 * g4 + r) * LDA + col] = (__bf16)acc[t][r];
      }
    } else {  // v transposed [head][dim][tok]; 4 regs = 4 consecutive toks
#pragma unroll
      for (int t = 0; t < 6; ++t) {
        const int head = t >> 1, dim = (t & 1) * 16 + l15;
        *(bf16x4*)&v_s[(head * 32 + dim) * LDV + rowb + 4 * g4] =
            __builtin_convertvector(acc[t], bf16x4);
      }
    }
  }

  __syncthreads();   // barrier #1: k_s/v_s visible; h region dead (P reuse ok)

  // ---------------- Phase 3: attention, head by head ----------------
  int qry[4], qrx[4];
#pragma unroll
  for (int r = 0; r < 4; ++r) {
    const int row = rowb + 4 * g4 + r;
    const int ti2 = row >> 3, tj2 = row & 7;
    qry[r] = (wy == 15) ? (ti2 < 4 ? 1 : 2) : 0;
    qrx[r] = (wx == 15) ? (tj2 < 4 ? 1 : 2) : 0;
  }
  const f32x4 zf = {0.f, 0.f, 0.f, 0.f};
  f32x4 ovA[3][2];
#pragma unroll
  for (int h = 0; h < 3; ++h) {
    const float* bh = biasf + h * 4096;
    float bv[4][4];
#pragma unroll
    for (int n = 0; n < 4; ++n)
#pragma unroll
      for (int r = 0; r < 4; ++r)
        bv[n][r] = bh[(rowb + 4 * g4 + r) * 64 + n * 16 + l15];

    f32x4 sc[4];
#pragma unroll
    for (int n = 0; n < 4; ++n) {
      bf16x8 bk = *(const bf16x8*)&k_s[(n * 16 + l15) * LDA + h * 32 + 8 * g4];
      sc[n] = __builtin_amdgcn_mfma_f32_16x16x32_bf16(aq3[h], bk, zf, 0, 0, 0);
    }
#pragma unroll
    for (int n = 0; n < 4; ++n) {
      const int colt = n * 16 + l15;
      const int ki = colt >> 3, kj = colt & 7;
      const int kry = (wy == 15) ? (ki < 4 ? 1 : 2) : 0;
      const int krx = (wx == 15) ? (kj < 4 ? 1 : 2) : 0;
#pragma unroll
      for (int r = 0; r < 4; ++r) {
        const float mk = (qry[r] == kry && qrx[r] == krx) ? 0.f : -100.f;
        sc[n][r] += bv[n][r] + mk;
      }
    }
    float mx[4], sm[4];
#pragma unroll
    for (int r = 0; r < 4; ++r) {
      float m = fmaxf(fmaxf(sc[0][r], sc[1][r]), fmaxf(sc[2][r], sc[3][r]));
      m = fmaxf(m, __shfl_xor(m, 1)); m = fmaxf(m, __shfl_xor(m, 2));
      m = fmaxf(m, __shfl_xor(m, 4)); m = fmaxf(m, __shfl_xor(m, 8));
      mx[r] = m; sm[r] = 0.f;
    }
#pragma unroll
    for (int n = 0; n < 4; ++n)
#pragma unroll
      for (int r = 0; r < 4; ++r) {
        float p = __expf(sc[n][r] - mx[r]); sc[n][r] = p; sm[r] += p;
      }
#pragma unroll
    for (int r = 0; r < 4; ++r) {
      float s2 = sm[r];
      s2 += __shfl_xor(s2, 1); s2 += __shfl_xor(s2, 2);
      s2 += __shfl_xor(s2, 4); s2 += __shfl_xor(s2, 8);
      sm[r] = __builtin_amdgcn_rcpf(s2);
    }
    // P -> h_s cols 0..63 (over dead h; wave-local rows)
#pragma unroll
    for (int n = 0; n < 4; ++n)
#pragma unroll
      for (int r = 0; r < 4; ++r)
        h_s[(rowb + 4 * g4 + r) * LDA + n * 16 + l15] = (__bf16)sc[n][r];
    f32x4 ov[2] = {zf, zf};
#pragma unroll
    for (int ks = 0; ks < 2; ++ks) {
      bf16x8 pa = *(const bf16x8*)&h_s[(rowb + l15) * LDA + ks * 32 + 8 * g4];
#pragma unroll
      for (int t2 = 0; t2 < 2; ++t2) {
        bf16x8 vb2 = *(const bf16x8*)&v_s[(h * 32 + t2 * 16 + l15) * LDV + ks * 32 + 8 * g4];
        ov[t2] = __builtin_amdgcn_mfma_f32_16x16x32_bf16(pa, vb2, ov[t2], 0, 0, 0);
      }
    }
#pragma unroll
    for (int t2 = 0; t2 < 2; ++t2)
#pragma unroll
      for (int r = 0; r < 4; ++r)
        ovA[h][t2][r] = ov[t2][r] * sm[r];
  }
  // flush attn-out to h_s (overwrites dead P; wave-local rows)
#pragma unroll
  for (int h = 0; h < 3; ++h)
#pragma unroll
    for (int t2 = 0; t2 < 2; ++t2)
#pragma unroll
      for (int r = 0; r < 4; ++r)
        h_s[(rowb + 4 * g4 + r) * LDA + h * 32 + t2 * 16 + l15] = (__bf16)ovA[h][t2][r];
  // no barrier: proj reads only own-wave rows

  // ---------------- Phase 4: output projection (B-frags direct) -------------
  f32x4 po[6];
#pragma unroll
  for (int t = 0; t < 6; ++t) po[t] = zf;
#pragma unroll
  for (int ks = 0; ks < 3; ++ks) {
    bf16x8 a = *(const bf16x8*)&h_s[(rowb + l15) * LDA + ks * 32 + 8 * g4];
#pragma unroll
    for (int t = 0; t < 6; ++t) {
      bf16x8 bb = *(const bf16x8*)(fbase + (size_t)(54 + t * 3 + ks) * 512);
      po[t] = __builtin_amdgcn_mfma_f32_16x16x32_bf16(a, bb, po[t], 0, 0, 0);
    }
  }

  // ---------------- Phase 4.5: residual + LN2 fully in registers ------------
  size_t gbase[4];
  float xm[6][4];
#pragma unroll
  for (int r = 0; r < 4; ++r) {
    const int row = rowb + 4 * g4 + r;
    const int ti2 = row >> 3, tj2 = row & 7;
    const int iy = (wy * 8 + ti2 + SHIFT) & 127;
    const int ix = (wx * 8 + tj2 + SHIFT) & 127;
    gbase[r] = ((size_t)(b * 16384 + iy * 128 + ix)) * 96;
#pragma unroll
    for (int t = 0; t < 6; ++t)
      xm[t][r] = x[gbase[r] + t * 16 + l15] + po[t][r];
  }
  {
    float g6[6], b6[6];
#pragma unroll
    for (int t = 0; t < 6; ++t) { g6[t] = ln2g[t * 16 + l15]; b6[t] = ln2b[t * 16 + l15]; }
#pragma unroll
    for (int r = 0; r < 4; ++r) {
      float s = 0.f, ss = 0.f;
#pragma unroll
      for (int t = 0; t < 6; ++t) { s += xm[t][r]; ss += xm[t][r] * xm[t][r]; }
      s  += __shfl_xor(s, 1);  s  += __shfl_xor(s, 2);
      s  += __shfl_xor(s, 4);  s  += __shfl_xor(s, 8);
      ss += __shfl_xor(ss, 1); ss += __shfl_xor(ss, 2);
      ss += __shfl_xor(ss, 4); ss += __shfl_xor(ss, 8);
      const float mean = s * (1.f / 96.f);
      const float var  = ss * (1.f / 96.f) - mean * mean;
      const float rstd = rsqrtf(var + 1e-5f);
#pragma unroll
      for (int t = 0; t < 6; ++t) {
        const float h2 = (xm[t][r] - mean) * rstd * g6[t] + b6[t];
        h_s[(rowb + 4 * g4 + r) * LDA + t * 16 + l15] = (__bf16)h2;
      }
    }
  }

  __syncthreads();   // barrier #2: all k/v reads done -> regions reusable

  // ---------------- Phase 5: MLP, 6 chunks of 64 hidden cols ----------------
  f32x4 acc[6];
#pragma unroll
  for (int t = 0; t < 6; ++t) acc[t] = zf;

  for (int cc = 0; cc < 6; ++cc) {
    {  // stage w1 chunk [64 outcols][96 k]
      const __bf16* wsrc = ws + WS_W1T + cc * 6144;
#pragma unroll
      for (int m = tid; m < 768; m += 256) {
        const int row = m / 12, q4 = m - row * 12;
        *(uint4*)&w_s[row * LDW1 + q4 * 8] = *(const uint4*)&wsrc[row * 96 + q4 * 8];
      }
    }
    __syncthreads();
    f32x4 ua[4];
#pragma unroll
    for (int t = 0; t < 4; ++t) ua[t] = zf;
#pragma unroll
    for (int ks = 0; ks < 3; ++ks) {
      bf16x8 a = *(const bf16x8*)&h_s[(rowb + l15) * LDA + ks * 32 + 8 * g4];
#pragma unroll
      for (int t = 0; t < 4; ++t) {
        bf16x8 bb = *(const bf16x8*)&w_s[(t * 16 + l15) * LDW1 + ks * 32 + 8 * g4];
        ua[t] = __builtin_amdgcn_mfma_f32_16x16x32_bf16(a, bb, ua[t], 0, 0, 0);
      }
    }
    // gelu -> u_s (wave-local rows)
#pragma unroll
    for (int t = 0; t < 4; ++t)
#pragma unroll
      for (int r = 0; r < 4; ++r) {
        const float v = ua[t][r];
        const float e = __expf(1.5957691216057308f * (v + 0.044715f * v * v * v));
        const float g = v - v * __builtin_amdgcn_rcpf(e + 1.f);
        u_s[(rowb + 4 * g4 + r) * LDU + t * 16 + l15] = (__bf16)g;
      }
    __syncthreads();   // all waves done reading w1 chunk
    {  // stage w2 chunk [96 outcols][64 j]
      const __bf16* wsrc = ws + WS_W2C + cc * 6144;
#pragma unroll
      for (int m = tid; m < 768; m += 256) {
        const int row = m >> 3, q4 = m & 7;
        *(uint4*)&w_s[row * LDW2 + q4 * 8] = *(const uint4*)&wsrc[row * 64 + q4 * 8];
      }
    }
    __syncthreads();
#pragma unroll
    for (int ks = 0; ks < 2; ++ks) {
      bf16x8 pa = *(const bf16x8*)&u_s[(rowb + l15) * LDU + ks * 32 + 8 * g4];
#pragma unroll
      for (int t = 0; t < 6; ++t) {
        bf16x8 bb = *(const bf16x8*)&w_s[(t * 16 + l15) * LDW2 + ks * 32 + 8 * g4];
        acc[t] = __builtin_amdgcn_mfma_f32_16x16x32_bf16(pa, bb, acc[t], 0, 0, 0);
      }
    }
    __syncthreads();   // w buffer reusable next chunk
  }

  // ---------------- Epilogue: out = x_mid + mlp ----------------
#pragma unroll
  for (int r = 0; r < 4; ++r)
#pragma unroll
    for (int t = 0; t < 6; ++t)
      out[gbase[r] + t * 16 + l15] = xm[t][r] + acc[t][r];
}

extern "C" void kernel_launch(void* const* d_in, const int* in_sizes, int n_in,
                              void* d_out, int out_size, void* d_ws, size_t ws_size,
                              hipStream_t stream) {
  (void)in_sizes; (void)n_in; (void)out_size; (void)ws_size;
  const float* x     = (const float*)d_in[0];
  const float* ln1g  = (const float*)d_in[1];
  const float* ln1b  = (const float*)d_in[2];
  const float* qkvw  = (const float*)d_in[3];
  const float* qkvb  = (const float*)d_in[4];
  const float* projw = (const float*)d_in[5];
  const float* btab  = (const float*)d_in[6];
  const float* ln2g  = (const float*)d_in[7];
  const float* ln2b  = (const float*)d_in[8];
  const float* w1    = (const float*)d_in[9];
  const float* w2    = (const float*)d_in[10];
  float* out = (float*)d_out;
  __bf16* ws = (__bf16*)d_ws;

  // 122880 items = 110592 weight elems + 12288 bias elems
  swin_prep_kernel<<<480, 256, 0, stream>>>(qkvw, projw, w1, w2, btab, ws);
  swin_block_kernel<<<4096, 256, 0, stream>>>(x, ln1g, ln1b, ws, qkvb, ln2g, ln2b, out);
}